// Round 3
// baseline (403.686 us; speedup 1.0000x reference)
//
#include <hip/hip_runtime.h>

// Sinkhorn (dustbin-augmented) fully fused, iterated in the EXP domain.
//
//   ev_j = 2^{v'_j}, eu_i = 2^{u'_i}, A = 2^{alpha*log2e}, K9 = 2^-9
//   eu_i  = K9 / (sum_j es_ij*ev_j + A*evd)        es_ij = 2^{s_ij*log2e}
//   eud   = (0.5/A) / (sum_j ev_j + evd)
//   ev_j  = K9 / (sum_i es_ij*eu_i + A*eud)
//   evd   = (0.5/A) / (sum_i eu_i + eud)
//   Z     = (log2(es) + log2(eu) + log2(ev) + 9) * ln2
//
// Block = 1024 threads = one batch. Thread (a=t>>5, bb=t&31) owns rows
// [8a,8a+8) x cols {4bb..4bb+3, 128+4bb..128+4bb+3}.

#define PS 260  // partial-row stride in floats

constexpr float L2E = 1.4426950408889634f;
constexpr float LN2 = 0.6931471805599453f;
constexpr float K9  = 0.001953125f;  // 2^-9

__device__ __forceinline__ float flog2(float x) { return __builtin_amdgcn_logf(x); }
__device__ __forceinline__ float fexp2(float x) { return __builtin_amdgcn_exp2f(x); }

// classic-DPP fused add (quad_perm / row_ror only — unambiguous GCN semantics)
template <int CTRL>
__device__ __forceinline__ float dpp_add(float x) {
    int y = __builtin_amdgcn_update_dpp(0, __builtin_bit_cast(int, x), CTRL, 0xF, 0xF, true);
    return x + __builtin_bit_cast(float, y);
}

// allreduce over the 32 lanes of a half-wave (the bb dimension)
__device__ __forceinline__ float reduce32(float x) {
    x = dpp_add<0xB1>(x);    // quad_perm [1,0,3,2] : xor 1
    x = dpp_add<0x4E>(x);    // quad_perm [2,3,0,1] : xor 2
    x = dpp_add<0x124>(x);   // row_ror:4           : quad fold
    x = dpp_add<0x128>(x);   // row_ror:8           : row uniform
    x += __shfl_xor(x, 16, 64);  // cross 16 (proven path)
    return x;
}

__device__ __forceinline__ float xor32_add(float x) {
    return x + __shfl_xor(x, 32, 64);  // proven path
}

__global__ __launch_bounds__(1024) void sinkhorn_kernel(
    const float* __restrict__ scores,
    const float* __restrict__ alpha_p,
    const int*   __restrict__ iters_p,
    float* __restrict__ out)
{
    const int bat = blockIdx.x;
    const int t   = threadIdx.x;
    const int a   = t >> 5;   // row-group: rows [8a, 8a+8)
    const int bb  = t & 31;   // col-group: cols 4bb.. and 128+4bb..
    const int w   = t >> 6;   // wave id 0..15

    const float alpha2    = alpha_p[0] * L2E;
    const float A         = fexp2(alpha2);
    const float halfOverA = fexp2(-1.0f - alpha2);
    const int iters = iters_p[0];

    __shared__ __align__(16) float sbuf[2][16 * PS];  // per-wave column partials
    __shared__ __align__(16) float vbuf[2][PS];       // ev (257 entries used)

    // ---- load scores once; keep es = 2^(s*log2e) in registers ----
    float es[8][8];
    const float* sp = scores + ((size_t)bat << 16) + ((size_t)a << 11) + (bb << 2);
    #pragma unroll
    for (int r = 0; r < 8; ++r) {
        const float4 x0 = *reinterpret_cast<const float4*>(sp + (r << 8));
        const float4 x1 = *reinterpret_cast<const float4*>(sp + (r << 8) + 128);
        es[r][0] = fexp2(x0.x * L2E);
        es[r][1] = fexp2(x0.y * L2E);
        es[r][2] = fexp2(x0.z * L2E);
        es[r][3] = fexp2(x0.w * L2E);
        es[r][4] = fexp2(x1.x * L2E);
        es[r][5] = fexp2(x1.y * L2E);
        es[r][6] = fexp2(x1.z * L2E);
        es[r][7] = fexp2(x1.w * L2E);
    }

    if (t < 257) vbuf[0][t] = 1.0f;   // v0 = 0  ->  ev = 1
    float eul[8];
    #pragma unroll
    for (int r = 0; r < 8; ++r) eul[r] = 1.0f;
    float eud = 1.0f;
    __syncthreads();

    for (int it = 0; it < iters; ++it) {
        const int cur = it & 1, nxt = cur ^ 1;

        // ---------------- row phase: eu from ev ----------------
        const float4 e0 = *reinterpret_cast<const float4*>(&vbuf[cur][bb << 2]);
        const float4 e1 = *reinterpret_cast<const float4*>(&vbuf[cur][128 + (bb << 2)]);
        const float evd = vbuf[cur][256];
        float evl[8] = {e0.x, e0.y, e0.z, e0.w, e1.x, e1.y, e1.z, e1.w};

        float sv = ((evl[0]+evl[1])+(evl[2]+evl[3]))+((evl[4]+evl[5])+(evl[6]+evl[7]));
        sv = reduce32(sv);                       // sum_j ev_j (all 256 cols)
        eud = halfOverA / (sv + evd);

        const float tdv = A * evd;
        #pragma unroll
        for (int r = 0; r < 8; ++r) {
            float p = es[r][0] * evl[0];
            #pragma unroll
            for (int c = 1; c < 8; ++c) p = fmaf(es[r][c], evl[c], p);
            p = reduce32(p);
            eul[r] = K9 / (p + tdv);
        }

        // ---------------- col phase: ev from (new) eu ----------------
        float us = ((eul[0]+eul[1])+(eul[2]+eul[3]))+((eul[4]+eul[5])+(eul[6]+eul[7]));
        float pc[8];
        #pragma unroll
        for (int c = 0; c < 8; ++c) {
            float q = es[0][c] * eul[0];
            #pragma unroll
            for (int r = 1; r < 8; ++r) q = fmaf(es[r][c], eul[r], q);
            pc[c] = q;
        }
        #pragma unroll
        for (int c = 0; c < 8; ++c) pc[c] = xor32_add(pc[c]);  // fold a=2w with 2w+1
        us = xor32_add(us);

        if ((t & 32) == 0) {  // lanes 0..31 of each wave write row w
            float* dst = &sbuf[cur][w * PS];
            *reinterpret_cast<float4*>(dst + (bb << 2)) =
                make_float4(pc[0], pc[1], pc[2], pc[3]);
            *reinterpret_cast<float4*>(dst + 128 + (bb << 2)) =
                make_float4(pc[4], pc[5], pc[6], pc[7]);
            if (bb == 0) dst[256] = us;
        }
        __syncthreads();

        if (t < 514) {  // 2 threads per column: halves of the 16 wave-partials
            const int col = t >> 1;
            const int r0  = (t & 1) << 3;
            float q0 = 0.f, q1 = 0.f;
            #pragma unroll
            for (int k = 0; k < 8; k += 2) {
                q0 += sbuf[cur][(r0 + k) * PS + col];
                q1 += sbuf[cur][(r0 + k + 1) * PS + col];
            }
            float q = q0 + q1;
            q = dpp_add<0xB1>(q);  // combine lanes t, t^1 (both active)
            if ((t & 1) == 0) {
                vbuf[nxt][col] = (col < 256) ? (K9 / (q + A * eud))
                                             : (halfOverA / (q + eud));
            }
        }
        __syncthreads();
    }

    // ---------------- output: Z = (s' + u' + v' + 9)*ln2 ----------------
    const int fin = iters & 1;
    const float vdust = flog2(vbuf[fin][256]);
    const float udust = flog2(eud);
    const float4 f0 = *reinterpret_cast<const float4*>(&vbuf[fin][bb << 2]);
    const float4 f1 = *reinterpret_cast<const float4*>(&vbuf[fin][128 + (bb << 2)]);
    float vl[8] = {flog2(f0.x), flog2(f0.y), flog2(f0.z), flog2(f0.w),
                   flog2(f1.x), flog2(f1.y), flog2(f1.z), flog2(f1.w)};

    const size_t ob = (size_t)bat * 66049;  // 257*257
    #pragma unroll
    for (int r = 0; r < 8; ++r) {
        const float up = flog2(eul[r]);
        const float su = up + 9.0f;
        float* rp = out + ob + (size_t)((a << 3) + r) * 257;
        #pragma unroll
        for (int c = 0; c < 4; ++c)
            rp[(bb << 2) + c] = (flog2(es[r][c]) + su + vl[c]) * LN2;
        #pragma unroll
        for (int c = 4; c < 8; ++c)
            rp[128 + (bb << 2) + (c - 4)] = (flog2(es[r][c]) + su + vl[c]) * LN2;
        if (bb == 0) rp[256] = (alpha2 + up + vdust + 9.0f) * LN2;  // dustbin col
    }
    // dustbin row (i=256), incl. corner at j=256
    if (t < 257) {
        const float vp = (t < 256) ? flog2(vbuf[fin][t]) : vdust;
        out[ob + 65792 + t] = (alpha2 + udust + vp + 9.0f) * LN2;
    }
}

extern "C" void kernel_launch(void* const* d_in, const int* in_sizes, int n_in,
                              void* d_out, int out_size, void* d_ws, size_t ws_size,
                              hipStream_t stream)
{
    const float* scores = (const float*)d_in[0];
    const float* alpha  = (const float*)d_in[1];
    const int*   iters  = (const int*)d_in[2];
    float* out = (float*)d_out;
    const int B = in_sizes[0] >> 16;
    hipLaunchKernelGGL(sinkhorn_kernel, dim3(B), dim3(1024), 0, stream,
                       scores, alpha, iters, out);
}